// Round 2
// 766.351 us; speedup vs baseline: 1.1531x; 1.1531x over previous
//
#include <hip/hip_runtime.h>

typedef _Float16 f16;
typedef _Float16 f16x8 __attribute__((ext_vector_type(8)));
typedef _Float16 f16x4 __attribute__((ext_vector_type(4)));
typedef float f32x4 __attribute__((ext_vector_type(4)));

#define MFMA16(a, b, c) __builtin_amdgcn_mfma_f32_16x16x32_f16((a), (b), (c), 0, 0, 0)

constexpr int DM = 1024;
constexpr int NH = 16;
constexpr int DEPTH = 64;
constexpr int SEQ = 2048;
constexpr int BATCH = 2;
constexpr int MTOT = BATCH * SEQ;  // 4096

// LDS XOR-swizzles: permute 16B slots within a row by row bits -> <=2-way conflicts.
// 64-half rows (128B): slot bits = half[5:3], xor with row&7.
__device__ __forceinline__ int swzA(int row, int off) {
  return row * 64 + (off ^ ((row & 7) << 3));
}
// 32-half rows (64B): slot bits = half[4:3], xor with (row>>1)&3.
__device__ __forceinline__ int swzG(int row, int off) {
  return row * 32 + (off ^ (((row >> 1) & 3) << 3));
}

// ---------------- fp32 -> fp16 convert ----------------
__global__ void k_cvt(const float* __restrict__ x, f16* __restrict__ y, int n) {
  int i = (blockIdx.x * blockDim.x + threadIdx.x) * 4;
  if (i >= n) return;
  const float4 v = *(const float4*)(x + i);
  f16x4 h;
  h[0] = (f16)v.x; h[1] = (f16)v.y; h[2] = (f16)v.z; h[3] = (f16)v.w;
  *(f16x4*)(y + i) = h;
}

// ---------------- GEMM: C[MTOTxDM] = A(f16) @ Bw(f32, cvt to f16) + bias ----------------
// FINAL=0: z=0/1 -> mode 0 (f16 split-head, Q/K), z=2 -> mode 2 (f16 head-transposed, V)
// FINAL=1: mode 1 (fp32 row-major, output projection)
template <int FINAL>
__global__ __launch_bounds__(256, 3) void k_gemm(const f16* __restrict__ A,
                                                 const float* __restrict__ B0,
                                                 const float* __restrict__ B1,
                                                 const float* __restrict__ B2,
                                                 const float* __restrict__ bias0,
                                                 const float* __restrict__ bias1,
                                                 const float* __restrict__ bias2,
                                                 void* __restrict__ o0,
                                                 void* __restrict__ o1,
                                                 void* __restrict__ o2) {
  constexpr int K = DM, N = DM;
  __shared__ f16 Al[128 * 32];  // [m][k] swizzled
  __shared__ f16 Bl[128 * 32];  // [n][k] swizzled
  const int z = blockIdx.z;
  const float* Bw   = FINAL ? B0 : (z == 0 ? B0 : (z == 1 ? B1 : B2));
  const float* bias = FINAL ? bias0 : (z == 0 ? bias0 : (z == 1 ? bias1 : bias2));
  void* outp        = FINAL ? o0 : (z == 0 ? o0 : (z == 1 ? o1 : o2));
  const int mode = FINAL ? 1 : (z == 2 ? 2 : 0);

  const int tid = threadIdx.x;
  const int lane = tid & 63;
  const int wave = tid >> 6;
  const int m0 = blockIdx.y * 128;
  const int n0 = blockIdx.x * 128;
  const int wr = (wave >> 1) * 64;
  const int wc = (wave & 1) * 64;
  const int lr = lane & 15;
  const int lk = (lane >> 4) * 8;

  f32x4 acc[4][4];
  for (int i = 0; i < 4; i++)
    for (int j = 0; j < 4; j++) acc[i][j] = (f32x4)0.0f;

  const int ar = tid >> 1, ak = (tid & 1) * 16;
  const int bn = (tid & 31) * 4, bk = (tid >> 5) * 4;

  // prefetch k-tile 0 into registers
  f16x8 a0r, a1r;
  float4 w0, w1, w2, w3;
  {
    const f16* ag = A + (size_t)(m0 + ar) * K + ak;
    a0r = *(const f16x8*)(ag);
    a1r = *(const f16x8*)(ag + 8);
    const float* bg = Bw + (size_t)bk * N + n0 + bn;
    w0 = *(const float4*)(bg);
    w1 = *(const float4*)(bg + N);
    w2 = *(const float4*)(bg + 2 * N);
    w3 = *(const float4*)(bg + 3 * N);
  }

  for (int k0 = 0; k0 < K; k0 += 32) {
    __syncthreads();
    *(f16x8*)(Al + swzG(ar, ak))     = a0r;
    *(f16x8*)(Al + swzG(ar, ak + 8)) = a1r;
    for (int j = 0; j < 4; j++) {
      f16x4 h;
      h[0] = (f16)(((const float*)&w0)[j]);
      h[1] = (f16)(((const float*)&w1)[j]);
      h[2] = (f16)(((const float*)&w2)[j]);
      h[3] = (f16)(((const float*)&w3)[j]);
      *(f16x4*)(Bl + swzG(bn + j, bk)) = h;
    }
    __syncthreads();
    if (k0 + 32 < K) {  // issue next-tile loads; they fly under the MFMAs below
      const f16* ag = A + (size_t)(m0 + ar) * K + (k0 + 32) + ak;
      a0r = *(const f16x8*)(ag);
      a1r = *(const f16x8*)(ag + 8);
      const float* bg = Bw + (size_t)(k0 + 32 + bk) * N + n0 + bn;
      w0 = *(const float4*)(bg);
      w1 = *(const float4*)(bg + N);
      w2 = *(const float4*)(bg + 2 * N);
      w3 = *(const float4*)(bg + 3 * N);
    }
    f16x8 af[4], bf[4];
    for (int i = 0; i < 4; i++)
      af[i] = *(const f16x8*)(Al + swzG(wr + i * 16 + lr, lk));
    for (int j = 0; j < 4; j++)
      bf[j] = *(const f16x8*)(Bl + swzG(wc + j * 16 + lr, lk));
    for (int i = 0; i < 4; i++)
      for (int j = 0; j < 4; j++) acc[i][j] = MFMA16(af[i], bf[j], acc[i][j]);
  }

  // epilogue: D[row=(lane>>4)*4+r][col=lane&15] (verified C/D layout)
  for (int j = 0; j < 4; j++) {
    const int n = n0 + wc + j * 16 + lr;
    const float bv = bias[n];
    for (int i = 0; i < 4; i++) {
      for (int r = 0; r < 4; r++) {
        const int m = m0 + wr + i * 16 + (lane >> 4) * 4 + r;
        const float val = acc[i][j][r] + bv;
        if (mode == 1) {
          ((float*)outp)[(size_t)m * N + n] = val;
        } else {
          const int b = m >> 11, s = m & 2047;
          const int h = n >> 6, d = n & 63;
          size_t idx;
          if (mode == 0)
            idx = ((size_t)(b * NH + h) * SEQ + s) * DEPTH + d;
          else
            idx = ((size_t)(b * NH + h) * DEPTH + d) * SEQ + s;
          ((f16*)outp)[idx] = (f16)val;
        }
      }
    }
  }
}

// ---------------- attention ----------------
// Swapped QK^T: a = mfma(K, Q) -> C[row=key][col=q]. Each lane holds 4 CONSECUTIVE
// keys for ONE q row (q = lane&15) -> coalesced float4 attn stores, ds_write_b64 Ps,
// and a 2-shfl row-sum reduce. All LDS tiles XOR-swizzled (were 16-way conflicts).
__global__ __launch_bounds__(256) void k_attn(const f16* __restrict__ qws,
                                              const f16* __restrict__ kws,
                                              const f16* __restrict__ vtws,
                                              float* __restrict__ attn,
                                              f16* __restrict__ ctx) {
  __shared__ f16 Qs[64 * 64];      // [qrow][d]   swizzled
  __shared__ f16 Ks[64 * 64];      // [key][d]    swizzled
  __shared__ f16 Vs[64 * 64];      // [d][key]    swizzled (V pre-transposed in ws)
  __shared__ f16 Ps[4][16 * 64];   // per-wave P tile [qrow16][key64] swizzled

  const int tid = threadIdx.x, lane = tid & 63, wave = tid >> 6;
  const int bh = blockIdx.y;
  const int q0 = blockIdx.x * 64;
  const int lr = lane & 15, g = lane >> 4, lk = g * 8;

  const f16* qb = qws + (size_t)bh * SEQ * DEPTH;
  const f16* kb = kws + (size_t)bh * SEQ * DEPTH;
  const f16* vb = vtws + (size_t)bh * DEPTH * SEQ;

  const int sr = tid >> 2, sc = (tid & 3) * 16;
  {
    const f16* qg = qb + (size_t)(q0 + sr) * 64 + sc;
    *(f16x8*)(Qs + swzA(sr, sc))     = *(const f16x8*)(qg);
    *(f16x8*)(Qs + swzA(sr, sc + 8)) = *(const f16x8*)(qg + 8);
  }
  __syncthreads();
  // Q as B-fragment (n = lane&15 = q row), k-halves 0/1 over depth 64
  const f16x8 qf0 = *(const f16x8*)(Qs + swzA(wave * 16 + lr, lk));
  const f16x8 qf1 = *(const f16x8*)(Qs + swzA(wave * 16 + lr, 32 + lk));

  // ---- pass 1: row sums of exp(logit) ----
  f16x8 kr0, kr1;
  {
    const f16* kg = kb + (size_t)sr * 64 + sc;
    kr0 = *(const f16x8*)(kg);
    kr1 = *(const f16x8*)(kg + 8);
  }
  float rsum = 0.f;
  for (int kt = 0; kt < SEQ; kt += 64) {
    __syncthreads();
    *(f16x8*)(Ks + swzA(sr, sc))     = kr0;
    *(f16x8*)(Ks + swzA(sr, sc + 8)) = kr1;
    __syncthreads();
    if (kt + 64 < SEQ) {
      const f16* kg = kb + (size_t)(kt + 64 + sr) * 64 + sc;
      kr0 = *(const f16x8*)(kg);
      kr1 = *(const f16x8*)(kg + 8);
    }
    for (int nb = 0; nb < 4; nb++) {
      f32x4 a = (f32x4)0.0f;
      f16x8 kf0 = *(const f16x8*)(Ks + swzA(nb * 16 + lr, lk));
      f16x8 kf1 = *(const f16x8*)(Ks + swzA(nb * 16 + lr, 32 + lk));
      a = MFMA16(kf0, qf0, a);
      a = MFMA16(kf1, qf1, a);
      rsum += (__expf(a[0] * 0.125f) + __expf(a[1] * 0.125f)) +
              (__expf(a[2] * 0.125f) + __expf(a[3] * 0.125f));
    }
  }
  // full row sum for q = lane&15: reduce across the 4 lane-groups
  rsum += __shfl_xor(rsum, 16);
  rsum += __shfl_xor(rsum, 32);
  const float rsinv = 1.0f / rsum;

  // ---- pass 2: recompute, coalesced attn writes, fused PV ----
  f32x4 cacc[4];
  for (int d = 0; d < 4; d++) cacc[d] = (f32x4)0.0f;
  float* ab = attn + (size_t)bh * SEQ * SEQ + (size_t)(q0 + wave * 16 + lr) * SEQ + g * 4;

  f16x8 vr0, vr1;
  {
    const f16* kg = kb + (size_t)sr * 64 + sc;
    kr0 = *(const f16x8*)(kg);
    kr1 = *(const f16x8*)(kg + 8);
    const f16* vg = vb + (size_t)sr * SEQ + sc;
    vr0 = *(const f16x8*)(vg);
    vr1 = *(const f16x8*)(vg + 8);
  }
  f16* Psw = Ps[wave];

  for (int kt = 0; kt < SEQ; kt += 64) {
    __syncthreads();
    *(f16x8*)(Ks + swzA(sr, sc))     = kr0;
    *(f16x8*)(Ks + swzA(sr, sc + 8)) = kr1;
    *(f16x8*)(Vs + swzA(sr, sc))     = vr0;
    *(f16x8*)(Vs + swzA(sr, sc + 8)) = vr1;
    __syncthreads();
    if (kt + 64 < SEQ) {
      const f16* kg = kb + (size_t)(kt + 64 + sr) * 64 + sc;
      kr0 = *(const f16x8*)(kg);
      kr1 = *(const f16x8*)(kg + 8);
      const f16* vg = vb + (size_t)sr * SEQ + kt + 64 + sc;
      vr0 = *(const f16x8*)(vg);
      vr1 = *(const f16x8*)(vg + 8);
    }
    for (int nb = 0; nb < 4; nb++) {
      f32x4 a = (f32x4)0.0f;
      f16x8 kf0 = *(const f16x8*)(Ks + swzA(nb * 16 + lr, lk));
      f16x8 kf1 = *(const f16x8*)(Ks + swzA(nb * 16 + lr, 32 + lk));
      a = MFMA16(kf0, qf0, a);
      a = MFMA16(kf1, qf1, a);
      const float p0 = __expf(a[0] * 0.125f) * rsinv;
      const float p1 = __expf(a[1] * 0.125f) * rsinv;
      const float p2 = __expf(a[2] * 0.125f) * rsinv;
      const float p3 = __expf(a[3] * 0.125f) * rsinv;
      f32x4 pq;
      pq[0] = p0; pq[1] = p1; pq[2] = p2; pq[3] = p3;
      __builtin_nontemporal_store(pq, (f32x4*)(ab + kt + nb * 16));  // streaming 512MB
      f16x4 ph;
      ph[0] = (f16)p0; ph[1] = (f16)p1; ph[2] = (f16)p2; ph[3] = (f16)p3;
      *(f16x4*)(Psw + swzA(lr, nb * 16 + g * 4)) = ph;
    }
    __syncthreads();  // P C-layout -> A-layout via LDS round-trip
    for (int ks = 0; ks < 2; ks++) {
      f16x8 pf = *(const f16x8*)(Psw + swzA(lr, ks * 32 + lk));
      for (int d = 0; d < 4; d++) {
        f16x8 vf = *(const f16x8*)(Vs + swzA(d * 16 + lr, ks * 32 + lk));
        cacc[d] = MFMA16(pf, vf, cacc[d]);
      }
    }
  }

  // write ctx as f16 [b*SEQ+s][h*64+d] for the final projection GEMM
  const int b = bh >> 4, h = bh & 15;
  for (int d = 0; d < 4; d++) {
    for (int r = 0; r < 4; r++) {
      const int qrow = q0 + wave * 16 + g * 4 + r;
      ctx[(size_t)(b * SEQ + qrow) * DM + h * DEPTH + d * 16 + lr] = (f16)cacc[d][r];
    }
  }
}

extern "C" void kernel_launch(void* const* d_in, const int* in_sizes, int n_in,
                              void* d_out, int out_size, void* d_ws, size_t ws_size,
                              hipStream_t stream) {
  const float* X  = (const float*)d_in[0];
  const float* wq = (const float*)d_in[1];
  const float* bq = (const float*)d_in[2];
  const float* wk = (const float*)d_in[3];
  const float* bk = (const float*)d_in[4];
  const float* wv = (const float*)d_in[5];
  const float* bv = (const float*)d_in[6];
  const float* wo = (const float*)d_in[7];
  const float* bo = (const float*)d_in[8];

  char* ws = (char*)d_ws;
  f16* Xh  = (f16*)(ws);
  f16* Qw  = (f16*)(ws + ((size_t)8 << 20));
  f16* Kw  = (f16*)(ws + ((size_t)16 << 20));
  f16* Vw  = (f16*)(ws + ((size_t)24 << 20));
  f16* Ctx = (f16*)(ws + ((size_t)32 << 20));

  float* out  = (float*)d_out;
  float* attn = out + (size_t)MTOT * DM;

  k_cvt<<<dim3(MTOT * DM / 1024), dim3(256), 0, stream>>>(X, Xh, MTOT * DM);
  // fused Q/K/V projection: 768 blocks (3 blocks/CU) instead of 3x256
  k_gemm<0><<<dim3(DM / 128, MTOT / 128, 3), 256, 0, stream>>>(
      Xh, wq, wk, wv, bq, bk, bv, (void*)Qw, (void*)Kw, (void*)Vw);
  k_attn<<<dim3(SEQ / 64, BATCH * NH), 256, 0, stream>>>(Qw, Kw, Vw, attn, Ctx);
  k_gemm<1><<<dim3(DM / 128, MTOT / 128, 1), 256, 0, stream>>>(
      Ctx, wo, wo, wo, bo, bo, bo, (void*)out, (void*)out, (void*)out);
}